// Round 12
// baseline (98.844 us; speedup 1.0000x reference)
//
#include <hip/hip_runtime.h>
#include <hip/hip_bf16.h>

#define B_ 8
#define C_ 64
#define N_ 4096
#define K_ 20
#define T_ 3
#define O_ 64
#define P_ 20
#define NK_ (N_ * K_) /* 81920 */
#define BN_EPS 1e-5f
#define KG 5  /* k-slices per staged phase */

// workspace layout (float offsets)
#define WS_FEATT 0                           // B*N*C      = 2,097,152
#define WS_WT (WS_FEATT + B_ * N_ * C_)      // 245,760 f16 -> 122,880 slots
#define WS_RAW (WS_WT + 122880)              // B*O*N      = 2,097,152
#define WS_PART (WS_RAW + B_ * O_ * N_)      // 1024*64*2  =   131,072
#define WS_STATS (WS_PART + 131072)          // 128

typedef __attribute__((ext_vector_type(8))) _Float16 half8;
typedef __attribute__((ext_vector_type(2))) _Float16 half2v;
typedef __attribute__((ext_vector_type(2))) __fp16 fp16x2;
typedef __attribute__((ext_vector_type(16))) float f32x16;

union UH8 {
    uint4 u;
    half8 h;
    half2v h2[4];
};
union UH2 {
    unsigned u;
    half2v h;
    fp16x2 f;
};

__device__ inline unsigned cvt_pkrtz_u(float a, float b) {
    UH2 x;
    x.f = __builtin_amdgcn_cvt_pkrtz(a, b);
    return x.u;
}

// K0: feat[b][c][n] -> featT[b][n][c]. XCD-aligned with k_main's consumer swizzle.
__global__ void k_transpose_feat(const float* __restrict__ feat, float* __restrict__ featT) {
    __shared__ float t[64][65];
    int bid = blockIdx.x;  // 512
    int b = bid & 7;
    int n0 = (bid >> 3) << 6;
    int lx = threadIdx.x & 63, ly = threadIdx.x >> 6;  // 256 threads
    const float* fp = feat + b * C_ * N_;
#pragma unroll
    for (int cc = 0; cc < 16; ++cc) {
        int c = ly * 16 + cc;
        t[c][lx] = fp[c * N_ + n0 + lx];
    }
    __syncthreads();
    float* op = featT + (b * N_ + n0) * C_;
#pragma unroll
    for (int u = 0; u < 16; ++u) {
        int n = ly * 16 + u;
        op[n * C_ + lx] = t[lx][n];
    }
}

// K5: pack conv_w into f16 MFMA A-fragment order, per-wave contiguous:
// frag id = (wc*2+wo)*60 + k*3 + t ; within frag lane l: o = wo*32+(l&31),
// c = wc*16 + (l>>5)*8 + j. A wave's 60 frags (60 KB) are contiguous.
__global__ void k_pack_w(const float* __restrict__ cw, _Float16* __restrict__ Wh) {
    int e = blockIdx.x * 256 + threadIdx.x;  // 245760 total
    int j = e & 7;
    int l = (e >> 3) & 63;
    int frag = e >> 9;
    int t = frag % 3;
    int k = (frag / 3) % K_;
    int wcwo = frag / 60;
    int o = (wcwo & 1) * 32 + (l & 31);
    int c = (wcwo >> 1) * 16 + (l >> 5) * 8 + j;
    Wh[e] = (_Float16)cw[o * (C_ * T_ * K_) + (c * T_ + t) * K_ + k];
}

// K2: fused taylor + phase-batched MFMA contraction (R10 skeleton).
// Per phase: [write E from last phase's gathers][issue next gathers]
// [PRELOAD all 15 A-frags to regs][barrier][15 MFMAs]. A-frag loads are
// grouped -> one exposed L2 latency per phase instead of 15.
__global__ __launch_bounds__(512, 4) void k_main(const float* __restrict__ featT,
                                                 const _Float16* __restrict__ Wh,
                                                 const float* __restrict__ weights,
                                                 const float* __restrict__ gpc,
                                                 const int* __restrict__ idx,
                                                 float* __restrict__ raw,
                                                 float* __restrict__ part) {
    __shared__ unsigned short E[2][KG][32][68];  // f16, 43,520 B; pad 68 -> 2-way reads
    __shared__ union {
        unsigned tayH[T_][K_][32];  // 7,680 B : half2(tay,tay)
        float out[64][36];          // 9,216 B epilogue merge buffer
    } su;

    // XCD-aware bijective swizzle (1024 blocks, 8 XCDs): XCD = bid0%8 = b
    const int bid0 = blockIdx.x;
    const int bid = (bid0 & 7) * 128 + (bid0 >> 3);
    const int b = bid >> 7;
    const int n0 = (bid & 127) << 5;
    const int tid = threadIdx.x;
    const int lane = tid & 63;
    const int wv = tid >> 6;
    const int wc = wv & 3;    // c-slice 16*wc
    const int wo = wv >> 2;   // o-half 32*wo
    const int nl = lane & 31;
    const int kf = lane >> 5;
    const int row = tid >> 4, seg = tid & 15;  // staging: (gather row, 16B segment)

    const float* fb = featT + (size_t)b * N_ * C_;
    // this wave's contiguous Wh slice (60 frags); phase p slice = 15 frags
    const _Float16* WhW = Wh + (size_t)(wc * 2 + wo) * (K_ * T_ * 512);

    // --- read this row's 20 idx values, packed 2-per-VGPR (values < 4096)
    unsigned idxp[10];
    {
        const int4* ip4 = (const int4*)(idx + (size_t)(b * N_ + n0 + row) * K_);
#pragma unroll
        for (int q = 0; q < 5; ++q) {
            int4 v = ip4[q];
            idxp[q * 2 + 0] = (unsigned)v.x | ((unsigned)v.y << 16);
            idxp[q * 2 + 1] = (unsigned)v.z | ((unsigned)v.w << 16);
        }
    }
#define IDXAT(kidx) ((idxp[(kidx) >> 1] >> (((kidx)&1) * 16)) & 0xffffu)

    // --- issue phase-0 gathers immediately (fly under the taylor stream)
    float4 gA[KG];
#pragma unroll
    for (int kk = 0; kk < KG; ++kk)
        gA[kk] = *(const float4*)(fb + (size_t)IDXAT(kk) * C_ + seg * 4);

    // --- fused taylor for this block's 32-n slice (coalesced weights stream)
    {
        const float* gpcb = gpc + (size_t)b * 3 * NK_ + n0 * K_;
        const float* wb0 = weights + (size_t)b * P_ * T_ * NK_ + n0 * K_;
        for (int e = tid; e < 32 * K_; e += 512) {
            float X = gpcb[e];
            float Y = gpcb[NK_ + e];
            float Z = gpcb[2 * NK_ + e];
            float XX = X * X, YY = Y * Y, ZZ = Z * Z;
            float XY = X * Y, XZ = X * Z, YZ = Y * Z;
            float terms[20];
            terms[0] = 1.f; terms[1] = X;      terms[2] = Y;       terms[3] = Z;
            terms[4] = XX;  terms[5] = YY;     terms[6] = ZZ;
            terms[7] = XX * X; terms[8] = YY * Y; terms[9] = ZZ * Z;
            terms[10] = XY; terms[11] = XZ;    terms[12] = YZ;
            terms[13] = X * XY;
            terms[14] = X * XZ;
            terms[15] = Y * YZ;
            terms[16] = Y * XY;
            terms[17] = Z * XZ;
            terms[18] = Z * YZ;
            terms[19] = XY * Z;
            float a0 = 0.f, a1 = 0.f, a2 = 0.f;
            const float* wp = wb0 + e;
#pragma unroll
            for (int p = 0; p < P_; ++p) {
                float tp = terms[p];
                a0 += wp[0] * tp;
                a1 += wp[(size_t)NK_] * tp;
                a2 += wp[2 * (size_t)NK_] * tp;
                wp += 3 * (size_t)NK_;
            }
            int n = e / K_, k = e - n * K_;
            su.tayH[0][k][n] = cvt_pkrtz_u(a0, a0);
            su.tayH[1][k][n] = cvt_pkrtz_u(a1, a1);
            su.tayH[2][k][n] = cvt_pkrtz_u(a2, a2);
        }
    }

    f32x16 acc;
#pragma unroll
    for (int i = 0; i < 16; ++i) acc[i] = 0.f;

    // --- 4 phases
#pragma unroll
    for (int p = 0; p < 4; ++p) {
        // write E[p&1] from gathers issued last phase (full phase of slack).
        // Safe: previous reader of this buffer was compute p-2, sequenced
        // before barrier p-1 in every wave.
#pragma unroll
        for (int kk = 0; kk < KG; ++kk) {
            uint2 w;
            w.x = cvt_pkrtz_u(gA[kk].x, gA[kk].y);
            w.y = cvt_pkrtz_u(gA[kk].z, gA[kk].w);
            *(uint2*)&E[p & 1][kk][row][seg * 4] = w;
        }
        // issue next phase's gathers
        if (p + 1 < 4) {
#pragma unroll
            for (int kk = 0; kk < KG; ++kk)
                gA[kk] = *(const float4*)(fb + (size_t)IDXAT((p + 1) * KG + kk) * C_ + seg * 4);
        }
        // preload this wave's 15 A-fragments (contiguous 15 KB) -> grouped issue
        UH8 ar[KG][3];
#pragma unroll
        for (int kk = 0; kk < KG; ++kk)
#pragma unroll
            for (int t = 0; t < 3; ++t)
                ar[kk][t].u =
                    *(const uint4*)(WhW + (((p * KG + kk) * 3 + t) << 9) + lane * 8);
        __syncthreads();  // E[p&1] published
        // compute: 15 MFMAs, A from regs, B from LDS
#pragma unroll
        for (int kk = 0; kk < KG; ++kk) {
            UH8 gv;
            gv.u = *(const uint4*)&E[p & 1][kk][nl][wc * 16 + kf * 8];
            const int k = p * KG + kk;
#pragma unroll
            for (int t = 0; t < 3; ++t) {
                UH2 tv;
                tv.u = su.tayH[t][k][nl];
                UH8 bv;
#pragma unroll
                for (int i = 0; i < 4; ++i) bv.h2[i] = gv.h2[i] * tv.h;  // v_pk_mul_f16
                acc = __builtin_amdgcn_mfma_f32_32x32x16_f16(ar[kk][t].h, bv.h, acc, 0, 0, 0);
            }
        }
    }

    __syncthreads();  // all reads of E/tayH done; su.out overlays tayH
    // --- serialized cross-wave c-merge (deterministic)
#pragma unroll 1
    for (int ww = 0; ww < 4; ++ww) {
        if (wc == ww) {
#pragma unroll
            for (int rr = 0; rr < 16; ++rr) {
                int orow = wo * 32 + (rr & 3) + ((rr >> 2) << 3) + (kf << 2);
                if (ww == 0)
                    su.out[orow][nl] = acc[rr];
                else
                    su.out[orow][nl] += acc[rr];
            }
        }
        __syncthreads();
    }

    {  // write raw tile: o = tid>>3, 4-float segment
        int o = tid >> 3, sg = tid & 7;
        float4* dst = (float4*)(raw + ((b * O_ + o) * N_) + n0 + sg * 4);
        const float* srow = &su.out[o][sg * 4];
        *dst = make_float4(srow[0], srow[1], srow[2], srow[3]);
    }
    if (tid < 64) {  // per-block BN partial sums over 32 n
        float s1 = 0.f, s2 = 0.f;
#pragma unroll 8
        for (int n = 0; n < 32; ++n) {
            float v = su.out[tid][n];
            s1 += v;
            s2 += v * v;
        }
        part[(bid * 64 + tid) * 2 + 0] = s1;
        part[(bid * 64 + tid) * 2 + 1] = s2;
    }
}

// K3: reduce 1024 block-partials per channel -> scale/shift (deterministic)
__global__ void k_bnstats(const float* __restrict__ part, const float* __restrict__ gamma,
                          const float* __restrict__ beta, float* __restrict__ stats) {
    int o = blockIdx.x;
    int tid = threadIdx.x;
    __shared__ float s1s[256], s2s[256];
    float s1 = 0.f, s2 = 0.f;
    for (int j = tid; j < 1024; j += 256) {
        s1 += part[(j * 64 + o) * 2 + 0];
        s2 += part[(j * 64 + o) * 2 + 1];
    }
    s1s[tid] = s1;
    s2s[tid] = s2;
    __syncthreads();
    for (int s = 128; s > 0; s >>= 1) {
        if (tid < s) {
            s1s[tid] += s1s[tid + s];
            s2s[tid] += s2s[tid + s];
        }
        __syncthreads();
    }
    if (tid == 0) {
        const float cnt = (float)(B_ * N_);
        float mean = s1s[0] / cnt;
        float var = s2s[0] / cnt - mean * mean;
        float sc = gamma[o] * rsqrtf(var + BN_EPS);
        stats[o * 2 + 0] = sc;
        stats[o * 2 + 1] = beta[o] - mean * sc;
    }
}

// K4: normalize + ReLU, float4
__global__ void k_finalize(const float* __restrict__ raw, const float* __restrict__ stats,
                           float* __restrict__ out) {
    int e = (blockIdx.x * 256 + threadIdx.x) * 4;
    int o = (e >> 12) & 63;
    float sc = stats[o * 2 + 0], sh = stats[o * 2 + 1];
    float4 v = *(const float4*)(raw + e);
    v.x = fmaxf(v.x * sc + sh, 0.f);
    v.y = fmaxf(v.y * sc + sh, 0.f);
    v.z = fmaxf(v.z * sc + sh, 0.f);
    v.w = fmaxf(v.w * sc + sh, 0.f);
    *(float4*)(out + e) = v;
}

extern "C" void kernel_launch(void* const* d_in, const int* in_sizes, int n_in,
                              void* d_out, int out_size, void* d_ws, size_t ws_size,
                              hipStream_t stream) {
    const float* feat = (const float*)d_in[0];
    const int* idx = (const int*)d_in[1];
    const float* gpc = (const float*)d_in[2];
    const float* weights = (const float*)d_in[3];
    const float* conv_w = (const float*)d_in[4];
    const float* gamma = (const float*)d_in[5];
    const float* beta = (const float*)d_in[6];
    float* out = (float*)d_out;
    float* ws = (float*)d_ws;

    float* featT = ws + WS_FEATT;
    _Float16* Wh = (_Float16*)(ws + WS_WT);
    float* raw = ws + WS_RAW;
    float* part = ws + WS_PART;
    float* stats = ws + WS_STATS;

    hipLaunchKernelGGL(k_transpose_feat, dim3(512), dim3(256), 0, stream, feat, featT);
    hipLaunchKernelGGL(k_pack_w, dim3((K_ * T_ * C_ * O_) / 256), dim3(256), 0, stream, conv_w,
                       Wh);
    hipLaunchKernelGGL(k_main, dim3(B_ * (N_ / 32)), dim3(512), 0, stream, featT, Wh, weights,
                       gpc, idx, raw, part);
    hipLaunchKernelGGL(k_bnstats, dim3(O_), dim3(256), 0, stream, part, gamma, beta, stats);
    hipLaunchKernelGGL(k_finalize, dim3(B_ * O_ * N_ / 4 / 256), dim3(256), 0, stream, raw, stats,
                       out);
}

// Round 13
// 92.489 us; speedup vs baseline: 1.0687x; 1.0687x over previous
//
#include <hip/hip_runtime.h>
#include <hip/hip_bf16.h>

#define B_ 8
#define C_ 64
#define N_ 4096
#define K_ 20
#define T_ 3
#define O_ 64
#define P_ 20
#define NK_ (N_ * K_) /* 81920 */
#define BN_EPS 1e-5f

// workspace layout (float offsets)
#define WS_FEATH 0                           // B*N*C f16 -> 1,048,576 float slots
#define WS_WT (WS_FEATH + 1048576)           // 245,760 f16 -> 122,880 slots
#define WS_RAW (WS_WT + 122880)              // B*O*N      = 2,097,152
#define WS_PART (WS_RAW + B_ * O_ * N_)      // 1024*64*2  =   131,072
#define WS_STATS (WS_PART + 131072)          // 128

typedef __attribute__((ext_vector_type(8))) _Float16 half8;
typedef __attribute__((ext_vector_type(2))) _Float16 half2v;
typedef __attribute__((ext_vector_type(2))) __fp16 fp16x2;
typedef __attribute__((ext_vector_type(16))) float f32x16;

union UH8 {
    uint4 u;
    half8 h;
    half2v h2[4];
};
union UH2 {
    unsigned u;
    half2v h;
    fp16x2 f;
};

__device__ inline unsigned cvt_pkrtz_u(float a, float b) {
    UH2 x;
    x.f = __builtin_amdgcn_cvt_pkrtz(a, b);
    return x.u;
}

// K0: feat[b][c][n] f32 -> featH[b][n][c] f16 (same RTZ cvt the MFMA path used
// after gathering -> downstream arithmetic is bit-identical to R10).
__global__ void k_transpose_feat(const float* __restrict__ feat,
                                 unsigned short* __restrict__ featH) {
    __shared__ float t[64][65];
    int bid = blockIdx.x;  // 512; XCD-aligned: bid%8 == b
    int b = bid & 7;
    int n0 = (bid >> 3) << 6;
    int lx = threadIdx.x & 63, ly = threadIdx.x >> 6;  // 256 threads
    const float* fp = feat + b * C_ * N_;
#pragma unroll
    for (int cc = 0; cc < 16; ++cc) {
        int c = ly * 16 + cc;
        t[c][lx] = fp[c * N_ + n0 + lx];
    }
    __syncthreads();
    unsigned short* op = featH + (size_t)(b * N_ + n0) * C_;
#pragma unroll
    for (int u = 0; u < 16; ++u) {
        int n = ly * 16 + u;
        op[n * C_ + lx] = (unsigned short)(cvt_pkrtz_u(t[lx][n], 0.f) & 0xffffu);
    }
}

// K5: pack conv_w into f16 MFMA A-fragment order, per-wave contiguous:
// frag id = (wc*2+wo)*60 + k*3 + t ; lane l: o = wo*32+(l&31), c = wc*16+(l>>5)*8+j
__global__ void k_pack_w(const float* __restrict__ cw, _Float16* __restrict__ Wh) {
    int e = blockIdx.x * 256 + threadIdx.x;  // 245760 total
    int j = e & 7;
    int l = (e >> 3) & 63;
    int frag = e >> 9;
    int t = frag % 3;
    int k = (frag / 3) % K_;
    int wcwo = frag / 60;
    int o = (wcwo & 1) * 32 + (l & 31);
    int c = (wcwo >> 1) * 16 + (l >> 5) * 8 + j;
    Wh[e] = (_Float16)cw[o * (C_ * T_ * K_) + (c * T_ + t) * K_ + k];
}

// K2: fused taylor + BARRIER-FREE MFMA k-loop.
// Block = (b, 32-n tile), 512 thr = 8 waves (wc = c-slice, wo = o-half).
// Lane gathers its own f16 B-row slice (n = lane&31 is lane-local in the MFMA
// B layout) -> no LDS staging, no barriers in the loop; tay is read-only LDS.
// Rolling 5-deep register buffer keeps gathers in flight.
__global__ __launch_bounds__(512, 4) void k_main(const unsigned short* __restrict__ featH,
                                                 const _Float16* __restrict__ Wh,
                                                 const float* __restrict__ weights,
                                                 const float* __restrict__ gpc,
                                                 const int* __restrict__ idx,
                                                 float* __restrict__ raw,
                                                 float* __restrict__ part) {
    __shared__ union {
        unsigned tayH[T_][K_][32];  // 7,680 B : half2(tay,tay)
        float out[64][36];          // 9,216 B epilogue merge buffer
    } su;

    // XCD-aware bijective swizzle (1024 blocks, 8 XCDs): XCD = bid0%8 = b
    const int bid0 = blockIdx.x;
    const int bid = (bid0 & 7) * 128 + (bid0 >> 3);
    const int b = bid >> 7;
    const int n0 = (bid & 127) << 5;
    const int tid = threadIdx.x;
    const int lane = tid & 63;
    const int wv = tid >> 6;
    const int wc = wv & 3;    // c-slice 16*wc
    const int wo = wv >> 2;   // o-half 32*wo
    const int nl = lane & 31;
    const int kf = lane >> 5;

    const unsigned short* fb16 = featH + (size_t)b * N_ * C_ + wc * 16 + kf * 8;
    const _Float16* WhW = Wh + (size_t)(wc * 2 + wo) * (K_ * T_ * 512) + lane * 8;

    // --- per-lane idx for row nl, packed 2-per-VGPR (values < 4096)
    unsigned idxp[10];
    {
        const int4* ip4 = (const int4*)(idx + (size_t)(b * N_ + n0 + nl) * K_);
#pragma unroll
        for (int q = 0; q < 5; ++q) {
            int4 v = ip4[q];
            idxp[q * 2 + 0] = (unsigned)v.x | ((unsigned)v.y << 16);
            idxp[q * 2 + 1] = (unsigned)v.z | ((unsigned)v.w << 16);
        }
    }
#define IDXAT(kidx) ((idxp[(kidx) >> 1] >> (((kidx)&1) * 16)) & 0xffffu)

    // --- rolling gather buffer: issue k=0..4 immediately (fly under taylor)
    UH8 gbuf[5];
#pragma unroll
    for (int kk = 0; kk < 5; ++kk)
        gbuf[kk].u = *(const uint4*)(fb16 + (size_t)IDXAT(kk) * C_);

    // --- fused taylor for this block's 32-n slice (coalesced weights stream)
    {
        const float* gpcb = gpc + (size_t)b * 3 * NK_ + n0 * K_;
        const float* wb0 = weights + (size_t)b * P_ * T_ * NK_ + n0 * K_;
        for (int e = tid; e < 32 * K_; e += 512) {
            float X = gpcb[e];
            float Y = gpcb[NK_ + e];
            float Z = gpcb[2 * NK_ + e];
            float XX = X * X, YY = Y * Y, ZZ = Z * Z;
            float XY = X * Y, XZ = X * Z, YZ = Y * Z;
            float terms[20];
            terms[0] = 1.f; terms[1] = X;      terms[2] = Y;       terms[3] = Z;
            terms[4] = XX;  terms[5] = YY;     terms[6] = ZZ;
            terms[7] = XX * X; terms[8] = YY * Y; terms[9] = ZZ * Z;
            terms[10] = XY; terms[11] = XZ;    terms[12] = YZ;
            terms[13] = X * XY;
            terms[14] = X * XZ;
            terms[15] = Y * YZ;
            terms[16] = Y * XY;
            terms[17] = Z * XZ;
            terms[18] = Z * YZ;
            terms[19] = XY * Z;
            float a0 = 0.f, a1 = 0.f, a2 = 0.f;
            const float* wp = wb0 + e;
#pragma unroll
            for (int p = 0; p < P_; ++p) {
                float tp = terms[p];
                a0 += wp[0] * tp;
                a1 += wp[(size_t)NK_] * tp;
                a2 += wp[2 * (size_t)NK_] * tp;
                wp += 3 * (size_t)NK_;
            }
            int n = e / K_, k = e - n * K_;
            su.tayH[0][k][n] = cvt_pkrtz_u(a0, a0);
            su.tayH[1][k][n] = cvt_pkrtz_u(a1, a1);
            su.tayH[2][k][n] = cvt_pkrtz_u(a2, a2);
        }
    }
    __syncthreads();  // tayH published; the ONLY barrier before the epilogue

    f32x16 acc;
#pragma unroll
    for (int i = 0; i < 16; ++i) acc[i] = 0.f;

    // --- barrier-free k-loop, fully unrolled; 5 gathers always in flight
#pragma unroll
    for (int k = 0; k < K_; ++k) {
        UH8 gv = gbuf[k % 5];
        if (k + 5 < K_)
            gbuf[k % 5].u = *(const uint4*)(fb16 + (size_t)IDXAT(k + 5) * C_);
#pragma unroll
        for (int t = 0; t < 3; ++t) {
            UH8 ar;
            ar.u = *(const uint4*)(WhW + ((k * 3 + t) << 9));
            UH2 tv;
            tv.u = su.tayH[t][k][nl];
            UH8 bv;
#pragma unroll
            for (int i = 0; i < 4; ++i) bv.h2[i] = gv.h2[i] * tv.h;  // v_pk_mul_f16
            acc = __builtin_amdgcn_mfma_f32_32x32x16_f16(ar.h, bv.h, acc, 0, 0, 0);
        }
    }

    __syncthreads();  // all tayH reads done; su.out overlays it
    // --- serialized cross-wave c-merge (deterministic)
#pragma unroll 1
    for (int ww = 0; ww < 4; ++ww) {
        if (wc == ww) {
#pragma unroll
            for (int rr = 0; rr < 16; ++rr) {
                int orow = wo * 32 + (rr & 3) + ((rr >> 2) << 3) + (kf << 2);
                if (ww == 0)
                    su.out[orow][nl] = acc[rr];
                else
                    su.out[orow][nl] += acc[rr];
            }
        }
        __syncthreads();
    }

    {  // write raw tile: o = tid>>3, 4-float segment
        int o = tid >> 3, sg = tid & 7;
        float4* dst = (float4*)(raw + ((b * O_ + o) * N_) + n0 + sg * 4);
        const float* srow = &su.out[o][sg * 4];
        *dst = make_float4(srow[0], srow[1], srow[2], srow[3]);
    }
    if (tid < 64) {  // per-block BN partial sums over 32 n
        float s1 = 0.f, s2 = 0.f;
#pragma unroll 8
        for (int n = 0; n < 32; ++n) {
            float v = su.out[tid][n];
            s1 += v;
            s2 += v * v;
        }
        part[(bid * 64 + tid) * 2 + 0] = s1;
        part[(bid * 64 + tid) * 2 + 1] = s2;
    }
}

// K3: reduce 1024 block-partials per channel -> scale/shift (deterministic)
__global__ void k_bnstats(const float* __restrict__ part, const float* __restrict__ gamma,
                          const float* __restrict__ beta, float* __restrict__ stats) {
    int o = blockIdx.x;
    int tid = threadIdx.x;
    __shared__ float s1s[256], s2s[256];
    float s1 = 0.f, s2 = 0.f;
    for (int j = tid; j < 1024; j += 256) {
        s1 += part[(j * 64 + o) * 2 + 0];
        s2 += part[(j * 64 + o) * 2 + 1];
    }
    s1s[tid] = s1;
    s2s[tid] = s2;
    __syncthreads();
    for (int s = 128; s > 0; s >>= 1) {
        if (tid < s) {
            s1s[tid] += s1s[tid + s];
            s2s[tid] += s2s[tid + s];
        }
        __syncthreads();
    }
    if (tid == 0) {
        const float cnt = (float)(B_ * N_);
        float mean = s1s[0] / cnt;
        float var = s2s[0] / cnt - mean * mean;
        float sc = gamma[o] * rsqrtf(var + BN_EPS);
        stats[o * 2 + 0] = sc;
        stats[o * 2 + 1] = beta[o] - mean * sc;
    }
}

// K4: normalize + ReLU, float4
__global__ void k_finalize(const float* __restrict__ raw, const float* __restrict__ stats,
                           float* __restrict__ out) {
    int e = (blockIdx.x * 256 + threadIdx.x) * 4;
    int o = (e >> 12) & 63;
    float sc = stats[o * 2 + 0], sh = stats[o * 2 + 1];
    float4 v = *(const float4*)(raw + e);
    v.x = fmaxf(v.x * sc + sh, 0.f);
    v.y = fmaxf(v.y * sc + sh, 0.f);
    v.z = fmaxf(v.z * sc + sh, 0.f);
    v.w = fmaxf(v.w * sc + sh, 0.f);
    *(float4*)(out + e) = v;
}

extern "C" void kernel_launch(void* const* d_in, const int* in_sizes, int n_in,
                              void* d_out, int out_size, void* d_ws, size_t ws_size,
                              hipStream_t stream) {
    const float* feat = (const float*)d_in[0];
    const int* idx = (const int*)d_in[1];
    const float* gpc = (const float*)d_in[2];
    const float* weights = (const float*)d_in[3];
    const float* conv_w = (const float*)d_in[4];
    const float* gamma = (const float*)d_in[5];
    const float* beta = (const float*)d_in[6];
    float* out = (float*)d_out;
    float* ws = (float*)d_ws;

    unsigned short* featH = (unsigned short*)(ws + WS_FEATH);
    _Float16* Wh = (_Float16*)(ws + WS_WT);
    float* raw = ws + WS_RAW;
    float* part = ws + WS_PART;
    float* stats = ws + WS_STATS;

    hipLaunchKernelGGL(k_transpose_feat, dim3(512), dim3(256), 0, stream, feat, featH);
    hipLaunchKernelGGL(k_pack_w, dim3((K_ * T_ * C_ * O_) / 256), dim3(256), 0, stream, conv_w,
                       Wh);
    hipLaunchKernelGGL(k_main, dim3(B_ * (N_ / 32)), dim3(512), 0, stream, featH, Wh, weights,
                       gpc, idx, raw, part);
    hipLaunchKernelGGL(k_bnstats, dim3(O_), dim3(256), 0, stream, part, gamma, beta, stats);
    hipLaunchKernelGGL(k_finalize, dim3(B_ * O_ * N_ / 4 / 256), dim3(256), 0, stream, raw, stats,
                       out);
}

// Round 14
// 76.495 us; speedup vs baseline: 1.2922x; 1.2091x over previous
//
#include <hip/hip_runtime.h>
#include <hip/hip_bf16.h>

#define B_ 8
#define C_ 64
#define N_ 4096
#define K_ 20
#define T_ 3
#define O_ 64
#define P_ 20
#define NK_ (N_ * K_) /* 81920 */
#define BN_EPS 1e-5f
#define KG 5  /* k-slices per staged phase */

// workspace layout (float offsets)
#define WS_FEATH 0                           // B*N*C f16 -> 1,048,576 float slots
#define WS_WT (WS_FEATH + 1048576)           // 245,760 f16 -> 122,880 slots
#define WS_RAW (WS_WT + 122880)              // B*O*N      = 2,097,152
#define WS_PART (WS_RAW + B_ * O_ * N_)      // 1024*64*2  =   131,072
#define WS_STATS (WS_PART + 131072)          // 128

typedef __attribute__((ext_vector_type(8))) _Float16 half8;
typedef __attribute__((ext_vector_type(2))) _Float16 half2v;
typedef __attribute__((ext_vector_type(2))) __fp16 fp16x2;
typedef __attribute__((ext_vector_type(16))) float f32x16;

union UH8 {
    uint4 u;
    half8 h;
    half2v h2[4];
};
union UH2 {
    unsigned u;
    half2v h;
    fp16x2 f;
};

__device__ inline unsigned cvt_pkrtz_u(float a, float b) {
    UH2 x;
    x.f = __builtin_amdgcn_cvt_pkrtz(a, b);
    return x.u;
}

// K0: feat[b][c][n] f32 -> featH[b][n][c] f16 (same RTZ cvt the staging used
// in R10 -> downstream arithmetic bit-identical). XCD-aligned: bid%8 == b.
__global__ void k_transpose_feat(const float* __restrict__ feat,
                                 unsigned short* __restrict__ featH) {
    __shared__ float t[64][65];
    int bid = blockIdx.x;  // 512
    int b = bid & 7;
    int n0 = (bid >> 3) << 6;
    int lx = threadIdx.x & 63, ly = threadIdx.x >> 6;  // 256 threads
    const float* fp = feat + b * C_ * N_;
#pragma unroll
    for (int cc = 0; cc < 16; ++cc) {
        int c = ly * 16 + cc;
        t[c][lx] = fp[c * N_ + n0 + lx];
    }
    __syncthreads();
    unsigned short* op = featH + (size_t)(b * N_ + n0) * C_;
#pragma unroll
    for (int u = 0; u < 16; ++u) {
        int n = ly * 16 + u;
        op[n * C_ + lx] = (unsigned short)(cvt_pkrtz_u(t[lx][n], 0.f) & 0xffffu);
    }
}

// K5: pack conv_w into f16 MFMA A-fragment order (R10 layout).
// frag id = ((k*3+t)*4+cc)*2+oh ; lane l: o = oh*32+(l&31), c = cc*16+(l>>5)*8+j
__global__ void k_pack_w(const float* __restrict__ cw, _Float16* __restrict__ Wh) {
    int e = blockIdx.x * 256 + threadIdx.x;  // 245760 total
    int j = e & 7;
    int l = (e >> 3) & 63;
    int frag = e >> 9;
    int oh = frag & 1;
    int cc = (frag >> 1) & 3;
    int kt = frag >> 3;
    int t = kt % 3, k = kt / 3;
    int o = oh * 32 + (l & 31);
    int c = cc * 16 + (l >> 5) * 8 + j;
    Wh[e] = (_Float16)cw[o * (C_ * T_ * K_) + (c * T_ + t) * K_ + k];
}

// K2: fused taylor + phase-batched MFMA (R10 skeleton, f16 staging, forced
// A-frag preload). Block = (b, 32-n tile), 512 thr = 8 waves.
// Per phase: [write E from last phase's gathers][issue next gathers]
// [preload 15 A-frags + keep-alive][barrier][15 MFMAs, load-free].
__global__ __launch_bounds__(512, 4) void k_main(const unsigned short* __restrict__ featH,
                                                 const _Float16* __restrict__ Wh,
                                                 const float* __restrict__ weights,
                                                 const float* __restrict__ gpc,
                                                 const int* __restrict__ idx,
                                                 float* __restrict__ raw,
                                                 float* __restrict__ part) {
    __shared__ unsigned short E[2][KG][32][68];  // f16, 43,520 B; pad 68 -> 2-way reads
    __shared__ union {
        unsigned tayH[T_][K_][32];  // 7,680 B : half2(tay,tay)
        float out[64][36];          // 9,216 B epilogue merge buffer
    } su;

    // XCD-aware bijective swizzle (1024 blocks, 8 XCDs): XCD = bid0%8 = b
    const int bid0 = blockIdx.x;
    const int bid = (bid0 & 7) * 128 + (bid0 >> 3);
    const int b = bid >> 7;
    const int n0 = (bid & 127) << 5;
    const int tid = threadIdx.x;
    const int lane = tid & 63;
    const int wv = tid >> 6;
    const int wc = wv & 3;    // c-slice 16*wc
    const int wo = wv >> 2;   // o-half 32*wo
    const int nl = lane & 31;
    const int kf = lane >> 5;
    const int row = tid >> 4, seg = tid & 15;  // staging: (gather row, 8B segment)

    const unsigned short* fbH = featH + (size_t)b * N_ * C_;

    // --- per-row idx values, packed 2-per-VGPR (values < 4096)
    unsigned idxp[10];
    {
        const int4* ip4 = (const int4*)(idx + (size_t)(b * N_ + n0 + row) * K_);
#pragma unroll
        for (int q = 0; q < 5; ++q) {
            int4 v = ip4[q];
            idxp[q * 2 + 0] = (unsigned)v.x | ((unsigned)v.y << 16);
            idxp[q * 2 + 1] = (unsigned)v.z | ((unsigned)v.w << 16);
        }
    }
#define IDXAT(kidx) ((idxp[(kidx) >> 1] >> (((kidx)&1) * 16)) & 0xffffu)

    // --- issue phase-0 gathers immediately (fly under the taylor stream)
    uint2 gA[KG];
#pragma unroll
    for (int kk = 0; kk < KG; ++kk)
        gA[kk] = *(const uint2*)(fbH + (size_t)IDXAT(kk) * C_ + seg * 4);

    // --- fused taylor for this block's 32-n slice (coalesced weights stream)
    {
        const float* gpcb = gpc + (size_t)b * 3 * NK_ + n0 * K_;
        const float* wb0 = weights + (size_t)b * P_ * T_ * NK_ + n0 * K_;
        for (int e = tid; e < 32 * K_; e += 512) {
            float X = gpcb[e];
            float Y = gpcb[NK_ + e];
            float Z = gpcb[2 * NK_ + e];
            float XX = X * X, YY = Y * Y, ZZ = Z * Z;
            float XY = X * Y, XZ = X * Z, YZ = Y * Z;
            float terms[20];
            terms[0] = 1.f; terms[1] = X;      terms[2] = Y;       terms[3] = Z;
            terms[4] = XX;  terms[5] = YY;     terms[6] = ZZ;
            terms[7] = XX * X; terms[8] = YY * Y; terms[9] = ZZ * Z;
            terms[10] = XY; terms[11] = XZ;    terms[12] = YZ;
            terms[13] = X * XY;
            terms[14] = X * XZ;
            terms[15] = Y * YZ;
            terms[16] = Y * XY;
            terms[17] = Z * XZ;
            terms[18] = Z * YZ;
            terms[19] = XY * Z;
            float a0 = 0.f, a1 = 0.f, a2 = 0.f;
            const float* wp = wb0 + e;
#pragma unroll
            for (int p = 0; p < P_; ++p) {
                float tp = terms[p];
                a0 += wp[0] * tp;
                a1 += wp[(size_t)NK_] * tp;
                a2 += wp[2 * (size_t)NK_] * tp;
                wp += 3 * (size_t)NK_;
            }
            int n = e / K_, k = e - n * K_;
            su.tayH[0][k][n] = cvt_pkrtz_u(a0, a0);
            su.tayH[1][k][n] = cvt_pkrtz_u(a1, a1);
            su.tayH[2][k][n] = cvt_pkrtz_u(a2, a2);
        }
    }

    f32x16 acc;
#pragma unroll
    for (int i = 0; i < 16; ++i) acc[i] = 0.f;

    // --- 4 phases; barrier 0 also publishes tayH
#pragma unroll
    for (int p = 0; p < 4; ++p) {
        // write E[p&1] from gathers issued last phase. Safe: prior reader of
        // this buffer (compute p-2) is sequenced before barrier p-1 everywhere.
#pragma unroll
        for (int kk = 0; kk < KG; ++kk)
            *(uint2*)&E[p & 1][kk][row][seg * 4] = gA[kk];
        // issue next phase's gathers (a full phase of slack)
        if (p + 1 < 4) {
#pragma unroll
            for (int kk = 0; kk < KG; ++kk)
                gA[kk] = *(const uint2*)(fbH + (size_t)IDXAT((p + 1) * KG + kk) * C_ + seg * 4);
        }
        // preload this phase's 15 A-fragments; keep-alive pins them in VGPRs
        // (LDS caps occupancy at 2 blocks/CU, so up to 128 VGPRs are free)
        UH8 ar[KG][3];
#pragma unroll
        for (int kk = 0; kk < KG; ++kk)
#pragma unroll
            for (int t = 0; t < 3; ++t)
                ar[kk][t].u = *(const uint4*)(
                    Wh + (size_t)(((((p * KG + kk) * 3 + t) * 4 + wc) * 2 + wo) * 64 + lane) * 8);
#pragma unroll
        for (int kk = 0; kk < KG; ++kk)
#pragma unroll
            for (int t = 0; t < 3; ++t)
                asm volatile("" : "+v"(ar[kk][t].u.x), "+v"(ar[kk][t].u.y),
                                  "+v"(ar[kk][t].u.z), "+v"(ar[kk][t].u.w));
        __syncthreads();  // E[p&1] (and, at p=0, tayH) published
        // compute: 15 MFMAs, A from regs, B from LDS only
#pragma unroll
        for (int kk = 0; kk < KG; ++kk) {
            UH8 gv;
            gv.u = *(const uint4*)&E[p & 1][kk][nl][wc * 16 + kf * 8];
            const int k = p * KG + kk;
#pragma unroll
            for (int t = 0; t < 3; ++t) {
                UH2 tv;
                tv.u = su.tayH[t][k][nl];
                UH8 bv;
#pragma unroll
                for (int i = 0; i < 4; ++i) bv.h2[i] = gv.h2[i] * tv.h;  // v_pk_mul_f16
                acc = __builtin_amdgcn_mfma_f32_32x32x16_f16(ar[kk][t].h, bv.h, acc, 0, 0, 0);
            }
        }
    }

    __syncthreads();  // all E/tayH reads done; su.out overlays tayH
    // --- serialized cross-wave c-merge (deterministic)
#pragma unroll 1
    for (int ww = 0; ww < 4; ++ww) {
        if (wc == ww) {
#pragma unroll
            for (int rr = 0; rr < 16; ++rr) {
                int orow = wo * 32 + (rr & 3) + ((rr >> 2) << 3) + (kf << 2);
                if (ww == 0)
                    su.out[orow][nl] = acc[rr];
                else
                    su.out[orow][nl] += acc[rr];
            }
        }
        __syncthreads();
    }

    {  // write raw tile: o = tid>>3, 4-float segment
        int o = tid >> 3, sg = tid & 7;
        float4* dst = (float4*)(raw + ((b * O_ + o) * N_) + n0 + sg * 4);
        const float* srow = &su.out[o][sg * 4];
        *dst = make_float4(srow[0], srow[1], srow[2], srow[3]);
    }
    if (tid < 64) {  // per-block BN partial sums over 32 n
        float s1 = 0.f, s2 = 0.f;
#pragma unroll 8
        for (int n = 0; n < 32; ++n) {
            float v = su.out[tid][n];
            s1 += v;
            s2 += v * v;
        }
        part[(bid * 64 + tid) * 2 + 0] = s1;
        part[(bid * 64 + tid) * 2 + 1] = s2;
    }
}

// K3: reduce 1024 block-partials per channel -> scale/shift (deterministic)
__global__ void k_bnstats(const float* __restrict__ part, const float* __restrict__ gamma,
                          const float* __restrict__ beta, float* __restrict__ stats) {
    int o = blockIdx.x;
    int tid = threadIdx.x;
    __shared__ float s1s[256], s2s[256];
    float s1 = 0.f, s2 = 0.f;
    for (int j = tid; j < 1024; j += 256) {
        s1 += part[(j * 64 + o) * 2 + 0];
        s2 += part[(j * 64 + o) * 2 + 1];
    }
    s1s[tid] = s1;
    s2s[tid] = s2;
    __syncthreads();
    for (int s = 128; s > 0; s >>= 1) {
        if (tid < s) {
            s1s[tid] += s1s[tid + s];
            s2s[tid] += s2s[tid + s];
        }
        __syncthreads();
    }
    if (tid == 0) {
        const float cnt = (float)(B_ * N_);
        float mean = s1s[0] / cnt;
        float var = s2s[0] / cnt - mean * mean;
        float sc = gamma[o] * rsqrtf(var + BN_EPS);
        stats[o * 2 + 0] = sc;
        stats[o * 2 + 1] = beta[o] - mean * sc;
    }
}

// K4: normalize + ReLU, float4
__global__ void k_finalize(const float* __restrict__ raw, const float* __restrict__ stats,
                           float* __restrict__ out) {
    int e = (blockIdx.x * 256 + threadIdx.x) * 4;
    int o = (e >> 12) & 63;
    float sc = stats[o * 2 + 0], sh = stats[o * 2 + 1];
    float4 v = *(const float4*)(raw + e);
    v.x = fmaxf(v.x * sc + sh, 0.f);
    v.y = fmaxf(v.y * sc + sh, 0.f);
    v.z = fmaxf(v.z * sc + sh, 0.f);
    v.w = fmaxf(v.w * sc + sh, 0.f);
    *(float4*)(out + e) = v;
}

extern "C" void kernel_launch(void* const* d_in, const int* in_sizes, int n_in,
                              void* d_out, int out_size, void* d_ws, size_t ws_size,
                              hipStream_t stream) {
    const float* feat = (const float*)d_in[0];
    const int* idx = (const int*)d_in[1];
    const float* gpc = (const float*)d_in[2];
    const float* weights = (const float*)d_in[3];
    const float* conv_w = (const float*)d_in[4];
    const float* gamma = (const float*)d_in[5];
    const float* beta = (const float*)d_in[6];
    float* out = (float*)d_out;
    float* ws = (float*)d_ws;

    unsigned short* featH = (unsigned short*)(ws + WS_FEATH);
    _Float16* Wh = (_Float16*)(ws + WS_WT);
    float* raw = ws + WS_RAW;
    float* part = ws + WS_PART;
    float* stats = ws + WS_STATS;

    hipLaunchKernelGGL(k_transpose_feat, dim3(512), dim3(256), 0, stream, feat, featH);
    hipLaunchKernelGGL(k_pack_w, dim3((K_ * T_ * C_ * O_) / 256), dim3(256), 0, stream, conv_w,
                       Wh);
    hipLaunchKernelGGL(k_main, dim3(B_ * (N_ / 32)), dim3(512), 0, stream, featH, Wh, weights,
                       gpc, idx, raw, part);
    hipLaunchKernelGGL(k_bnstats, dim3(O_), dim3(256), 0, stream, part, gamma, beta, stats);
    hipLaunchKernelGGL(k_finalize, dim3(B_ * O_ * N_ / 4 / 256), dim3(256), 0, stream, raw, stats,
                       out);
}

// Round 15
// 70.940 us; speedup vs baseline: 1.3933x; 1.0783x over previous
//
#include <hip/hip_runtime.h>
#include <hip/hip_bf16.h>

#define B_ 8
#define C_ 64
#define N_ 4096
#define K_ 20
#define T_ 3
#define O_ 64
#define P_ 20
#define NK_ (N_ * K_) /* 81920 */
#define BN_EPS 1e-5f
#define KG 5  /* k-slices per staged phase */

// workspace layout (float offsets)
#define WS_FEATT 0                           // B*N*C      = 2,097,152
#define WS_WT (WS_FEATT + B_ * N_ * C_)      // 245,760 f16 -> 122,880 slots
#define WS_RAW (WS_WT + 122880)              // B*O*N      = 2,097,152
#define WS_PART (WS_RAW + B_ * O_ * N_)      // 1024*64*2  =   131,072
#define WS_STATS (WS_PART + 131072)          // 128

typedef __attribute__((ext_vector_type(8))) _Float16 half8;
typedef __attribute__((ext_vector_type(2))) _Float16 half2v;
typedef __attribute__((ext_vector_type(2))) __fp16 fp16x2;
typedef __attribute__((ext_vector_type(16))) float f32x16;

union UH8 {
    uint4 u;
    half8 h;
    half2v h2[4];
};
union UH2 {
    unsigned u;
    half2v h;
    fp16x2 f;
};

__device__ inline unsigned cvt_pkrtz_u(float a, float b) {
    UH2 x;
    x.f = __builtin_amdgcn_cvt_pkrtz(a, b);
    return x.u;
}

// Barrier that publishes LDS (lgkmcnt(0)) but does NOT drain outstanding
// global loads (no vmcnt(0)) -- lets prefetched gathers stay in flight
// across the barrier (T3/T4). Compiler still inserts its own vmcnt waits
// before any USE of the loaded registers, so correctness is unaffected.
#define LGKM_BARRIER()                                      \
    do {                                                    \
        asm volatile("s_waitcnt lgkmcnt(0)" ::: "memory");  \
        __builtin_amdgcn_s_barrier();                       \
    } while (0)

// K0: feat[b][c][n] -> featT[b][n][c]. XCD-aligned with k_main's consumer swizzle.
__global__ void k_transpose_feat(const float* __restrict__ feat, float* __restrict__ featT) {
    __shared__ float t[64][65];
    int bid = blockIdx.x;  // 512; bid%8 == b
    int b = bid & 7;
    int n0 = (bid >> 3) << 6;
    int lx = threadIdx.x & 63, ly = threadIdx.x >> 6;  // 256 threads
    const float* fp = feat + b * C_ * N_;
#pragma unroll
    for (int cc = 0; cc < 16; ++cc) {
        int c = ly * 16 + cc;
        t[c][lx] = fp[c * N_ + n0 + lx];
    }
    __syncthreads();
    float* op = featT + (b * N_ + n0) * C_;
#pragma unroll
    for (int u = 0; u < 16; ++u) {
        int n = ly * 16 + u;
        op[n * C_ + lx] = t[lx][n];
    }
}

// K5: pack conv_w into f16 MFMA A-fragment order (R10 layout).
// frag id = ((k*3+t)*4+cc)*2+oh ; lane l: o = oh*32+(l&31), c = cc*16+(l>>5)*8+j
__global__ void k_pack_w(const float* __restrict__ cw, _Float16* __restrict__ Wh) {
    int e = blockIdx.x * 256 + threadIdx.x;  // 245760 total
    int j = e & 7;
    int l = (e >> 3) & 63;
    int frag = e >> 9;
    int oh = frag & 1;
    int cc = (frag >> 1) & 3;
    int kt = frag >> 3;
    int t = kt % 3, k = kt / 3;
    int o = oh * 32 + (l & 31);
    int c = cc * 16 + (l >> 5) * 8 + j;
    Wh[e] = (_Float16)cw[o * (C_ * T_ * K_) + (c * T_ + t) * K_ + k];
}

// K2: fused taylor + phase-batched MFMA contraction (R10 champion structure;
// ONLY change: phase barriers no longer drain vmcnt, so prefetched gathers
// genuinely span the barrier).
__global__ __launch_bounds__(512, 4) void k_main(const float* __restrict__ featT,
                                                 const _Float16* __restrict__ Wh,
                                                 const float* __restrict__ weights,
                                                 const float* __restrict__ gpc,
                                                 const int* __restrict__ idx,
                                                 float* __restrict__ raw,
                                                 float* __restrict__ part) {
    __shared__ unsigned short E[2][KG][32][68];  // f16, 43,520 B; pad 68 -> 2-way reads
    __shared__ union {
        unsigned tayH[T_][K_][32];  // 7,680 B : half2(tay,tay)
        float out[64][36];          // 9,216 B epilogue merge buffer
    } su;

    // XCD-aware bijective swizzle (1024 blocks, 8 XCDs): XCD = bid0%8 = b
    const int bid0 = blockIdx.x;
    const int bid = (bid0 & 7) * 128 + (bid0 >> 3);
    const int b = bid >> 7;
    const int n0 = (bid & 127) << 5;
    const int tid = threadIdx.x;
    const int lane = tid & 63;
    const int wv = tid >> 6;
    const int wc = wv & 3;    // c-slice 16*wc
    const int wo = wv >> 2;   // o-half 32*wo
    const int nl = lane & 31;
    const int kf = lane >> 5;
    const int row = tid >> 4, seg = tid & 15;  // staging: (gather row, 16B segment)

    const float* fb = featT + (size_t)b * N_ * C_;

    // --- read this row's 20 idx values, packed 2-per-VGPR (values < 4096)
    unsigned idxp[10];
    {
        const int4* ip4 = (const int4*)(idx + (size_t)(b * N_ + n0 + row) * K_);
#pragma unroll
        for (int q = 0; q < 5; ++q) {
            int4 v = ip4[q];
            idxp[q * 2 + 0] = (unsigned)v.x | ((unsigned)v.y << 16);
            idxp[q * 2 + 1] = (unsigned)v.z | ((unsigned)v.w << 16);
        }
    }
#define IDXAT(kidx) ((idxp[(kidx) >> 1] >> (((kidx)&1) * 16)) & 0xffffu)

    // --- issue phase-0 gathers immediately (fly under the taylor stream)
    float4 gA[KG], gB[KG];
#pragma unroll
    for (int kk = 0; kk < KG; ++kk)
        gA[kk] = *(const float4*)(fb + (size_t)IDXAT(kk) * C_ + seg * 4);

    // --- fused taylor for this block's 32-n slice (coalesced weights stream)
    {
        const float* gpcb = gpc + (size_t)b * 3 * NK_ + n0 * K_;
        const float* wb0 = weights + (size_t)b * P_ * T_ * NK_ + n0 * K_;
        for (int e = tid; e < 32 * K_; e += 512) {
            float X = gpcb[e];
            float Y = gpcb[NK_ + e];
            float Z = gpcb[2 * NK_ + e];
            float XX = X * X, YY = Y * Y, ZZ = Z * Z;
            float XY = X * Y, XZ = X * Z, YZ = Y * Z;
            float terms[20];
            terms[0] = 1.f; terms[1] = X;      terms[2] = Y;       terms[3] = Z;
            terms[4] = XX;  terms[5] = YY;     terms[6] = ZZ;
            terms[7] = XX * X; terms[8] = YY * Y; terms[9] = ZZ * Z;
            terms[10] = XY; terms[11] = XZ;    terms[12] = YZ;
            terms[13] = X * XY;
            terms[14] = X * XZ;
            terms[15] = Y * YZ;
            terms[16] = Y * XY;
            terms[17] = Z * XZ;
            terms[18] = Z * YZ;
            terms[19] = XY * Z;
            float a0 = 0.f, a1 = 0.f, a2 = 0.f;
            const float* wp = wb0 + e;
#pragma unroll
            for (int p = 0; p < P_; ++p) {
                float tp = terms[p];
                a0 += wp[0] * tp;
                a1 += wp[(size_t)NK_] * tp;
                a2 += wp[2 * (size_t)NK_] * tp;
                wp += 3 * (size_t)NK_;
            }
            int n = e / K_, k = e - n * K_;
            su.tayH[0][k][n] = cvt_pkrtz_u(a0, a0);
            su.tayH[1][k][n] = cvt_pkrtz_u(a1, a1);
            su.tayH[2][k][n] = cvt_pkrtz_u(a2, a2);
        }
    }

    // --- write E[0] from phase-0 gathers; issue phase-1 gathers
#pragma unroll
    for (int kk = 0; kk < KG; ++kk) {
        uint2 w;
        w.x = cvt_pkrtz_u(gA[kk].x, gA[kk].y);
        w.y = cvt_pkrtz_u(gA[kk].z, gA[kk].w);
        *(uint2*)&E[0][kk][row][seg * 4] = w;
    }
#pragma unroll
    for (int kk = 0; kk < KG; ++kk)
        gA[kk] = *(const float4*)(fb + (size_t)IDXAT(KG + kk) * C_ + seg * 4);
    LGKM_BARRIER();  // E[0] + tayH published; phase-1 gathers stay in flight

    f32x16 acc;
#pragma unroll
    for (int i = 0; i < 16; ++i) acc[i] = 0.f;

    // --- 4 phases; per phase: [issue p+2 loads][compute p][write p+1][barrier]
#pragma unroll
    for (int p = 0; p < 4; ++p) {
        if (p + 2 < 4) {
#pragma unroll
            for (int kk = 0; kk < KG; ++kk) {
                float4 v = *(const float4*)(fb + (size_t)IDXAT((p + 2) * KG + kk) * C_ + seg * 4);
                if (p & 1) gA[kk] = v; else gB[kk] = v;
            }
        }
#pragma unroll
        for (int kk = 0; kk < KG; ++kk) {
            UH8 gv;
            gv.u = *(const uint4*)&E[p & 1][kk][nl][wc * 16 + kf * 8];
            const int k = p * KG + kk;
#pragma unroll
            for (int t = 0; t < 3; ++t) {
                UH8 ar;
                ar.u = *(const uint4*)(Wh +
                                       (size_t)((((k * 3 + t) * 4 + wc) * 2 + wo) * 64 + lane) * 8);
                UH2 tv;
                tv.u = su.tayH[t][k][nl];
                UH8 bv;
#pragma unroll
                for (int i = 0; i < 4; ++i) bv.h2[i] = gv.h2[i] * tv.h;  // v_pk_mul_f16
                acc = __builtin_amdgcn_mfma_f32_32x32x16_f16(ar.h, bv.h, acc, 0, 0, 0);
            }
        }
        // write E[(p+1)&1] from gathers issued at iteration p-1 (compiler
        // inserts the needed vmcnt wait right here, not at the barrier)
        if (p + 1 < 4) {
#pragma unroll
            for (int kk = 0; kk < KG; ++kk) {
                float4 v = (p & 1) ? gB[kk] : gA[kk];
                uint2 w;
                w.x = cvt_pkrtz_u(v.x, v.y);
                w.y = cvt_pkrtz_u(v.z, v.w);
                *(uint2*)&E[(p + 1) & 1][kk][row][seg * 4] = w;
            }
        }
        LGKM_BARRIER();  // publish E writes; do NOT drain in-flight gathers
    }

    __syncthreads();  // epilogue: full barrier; su.out overlays tayH
    // --- serialized cross-wave c-merge (deterministic)
#pragma unroll 1
    for (int ww = 0; ww < 4; ++ww) {
        if (wc == ww) {
#pragma unroll
            for (int rr = 0; rr < 16; ++rr) {
                int orow = wo * 32 + (rr & 3) + ((rr >> 2) << 3) + (kf << 2);
                if (ww == 0)
                    su.out[orow][nl] = acc[rr];
                else
                    su.out[orow][nl] += acc[rr];
            }
        }
        __syncthreads();
    }

    {  // write raw tile: o = tid>>3, 4-float segment
        int o = tid >> 3, sg = tid & 7;
        float4* dst = (float4*)(raw + ((b * O_ + o) * N_) + n0 + sg * 4);
        const float* srow = &su.out[o][sg * 4];
        *dst = make_float4(srow[0], srow[1], srow[2], srow[3]);
    }
    if (tid < 64) {  // per-block BN partial sums over 32 n
        float s1 = 0.f, s2 = 0.f;
#pragma unroll 8
        for (int n = 0; n < 32; ++n) {
            float v = su.out[tid][n];
            s1 += v;
            s2 += v * v;
        }
        part[(bid * 64 + tid) * 2 + 0] = s1;
        part[(bid * 64 + tid) * 2 + 1] = s2;
    }
}

// K3: reduce 1024 block-partials per channel -> scale/shift (deterministic)
__global__ void k_bnstats(const float* __restrict__ part, const float* __restrict__ gamma,
                          const float* __restrict__ beta, float* __restrict__ stats) {
    int o = blockIdx.x;
    int tid = threadIdx.x;
    __shared__ float s1s[256], s2s[256];
    float s1 = 0.f, s2 = 0.f;
    for (int j = tid; j < 1024; j += 256) {
        s1 += part[(j * 64 + o) * 2 + 0];
        s2 += part[(j * 64 + o) * 2 + 1];
    }
    s1s[tid] = s1;
    s2s[tid] = s2;
    __syncthreads();
    for (int s = 128; s > 0; s >>= 1) {
        if (tid < s) {
            s1s[tid] += s1s[tid + s];
            s2s[tid] += s2s[tid + s];
        }
        __syncthreads();
    }
    if (tid == 0) {
        const float cnt = (float)(B_ * N_);
        float mean = s1s[0] / cnt;
        float var = s2s[0] / cnt - mean * mean;
        float sc = gamma[o] * rsqrtf(var + BN_EPS);
        stats[o * 2 + 0] = sc;
        stats[o * 2 + 1] = beta[o] - mean * sc;
    }
}

// K4: normalize + ReLU, float4
__global__ void k_finalize(const float* __restrict__ raw, const float* __restrict__ stats,
                           float* __restrict__ out) {
    int e = (blockIdx.x * 256 + threadIdx.x) * 4;
    int o = (e >> 12) & 63;
    float sc = stats[o * 2 + 0], sh = stats[o * 2 + 1];
    float4 v = *(const float4*)(raw + e);
    v.x = fmaxf(v.x * sc + sh, 0.f);
    v.y = fmaxf(v.y * sc + sh, 0.f);
    v.z = fmaxf(v.z * sc + sh, 0.f);
    v.w = fmaxf(v.w * sc + sh, 0.f);
    *(float4*)(out + e) = v;
}

extern "C" void kernel_launch(void* const* d_in, const int* in_sizes, int n_in,
                              void* d_out, int out_size, void* d_ws, size_t ws_size,
                              hipStream_t stream) {
    const float* feat = (const float*)d_in[0];
    const int* idx = (const int*)d_in[1];
    const float* gpc = (const float*)d_in[2];
    const float* weights = (const float*)d_in[3];
    const float* conv_w = (const float*)d_in[4];
    const float* gamma = (const float*)d_in[5];
    const float* beta = (const float*)d_in[6];
    float* out = (float*)d_out;
    float* ws = (float*)d_ws;

    float* featT = ws + WS_FEATT;
    _Float16* Wh = (_Float16*)(ws + WS_WT);
    float* raw = ws + WS_RAW;
    float* part = ws + WS_PART;
    float* stats = ws + WS_STATS;

    hipLaunchKernelGGL(k_transpose_feat, dim3(512), dim3(256), 0, stream, feat, featT);
    hipLaunchKernelGGL(k_pack_w, dim3((K_ * T_ * C_ * O_) / 256), dim3(256), 0, stream, conv_w,
                       Wh);
    hipLaunchKernelGGL(k_main, dim3(B_ * (N_ / 32)), dim3(512), 0, stream, featT, Wh, weights,
                       gpc, idx, raw, part);
    hipLaunchKernelGGL(k_bnstats, dim3(O_), dim3(256), 0, stream, part, gamma, beta, stats);
    hipLaunchKernelGGL(k_finalize, dim3(B_ * O_ * N_ / 4 / 256), dim3(256), 0, stream, raw, stats,
                       out);
}